// Round 1
// 241.071 us; speedup vs baseline: 1.4591x; 1.4591x over previous
//
#include <hip/hip_runtime.h>
#include <hip/hip_bf16.h>
#include <math.h>

// Problem constants
// x:(4,128,96,96) gate_w:(8,128,3,3) gate_bias:(8) expert_w:(8,128,128,3,3)
// expert_b:(8,128) shared_w:(128,128,3,3) shared_b:(128)  -> out:(4,128,96,96)

typedef __attribute__((ext_vector_type(8))) short short8;
typedef __attribute__((ext_vector_type(4))) float f32x4;

static __device__ __forceinline__ unsigned short f2bf(float f) {
    unsigned int u = __float_as_uint(f);
    unsigned int r = (u + 0x7FFFu + ((u >> 16) & 1u)) >> 16;
    return (unsigned short)r;
}

// ---------------------------------------------------------------------------
// Prep v2: expert_w (8,128,128,3,3) + shared_w (128,128,3,3) -> bf16 in
// MFMA-fragment order so the main kernel's A-loads are perfectly coalesced
// register loads (no LDS staging of weights at all).
//
// 16B-chunk index i:  et(81) | wv(4) | kc(4) | h(2) | lane(64)
//   lane = lm + 16*lq ; co = wv*32 + h*16 + lm ; k(ci) = kc*32 + lq*8 + d
//   value = w[e][co][k][tap]   (e==8 -> shared expert)
// ---------------------------------------------------------------------------
__global__ __launch_bounds__(256) void prep_kernel(
    const float* __restrict__ ew, const float* __restrict__ sw,
    unsigned short* __restrict__ pw)
{
    int i = blockIdx.x * 256 + threadIdx.x;      // 16B chunk index
    if (i >= 9 * 9 * 2048) return;
    int lane = i & 63;
    int h    = (i >> 6) & 1;
    int kc   = (i >> 7) & 3;
    int wv   = (i >> 9) & 3;
    int et   = i >> 11;
    int tap  = et % 9;
    int e    = et / 9;
    int lm = lane & 15, lq = lane >> 4;
    int co = wv * 32 + h * 16 + lm;
    int k0 = kc * 32 + lq * 8;
    unsigned short tmp[8];
    #pragma unroll
    for (int d = 0; d < 8; ++d) {
        int k = k0 + d;
        float v = (e < 8) ? ew[((e * 128 + co) * 128 + k) * 9 + tap]
                          : sw[(co * 128 + k) * 9 + tap];
        tmp[d] = f2bf(v);
    }
    *reinterpret_cast<uint4*>(pw + (size_t)i * 8) =
        *reinterpret_cast<const uint4*>(tmp);
}

// ---------------------------------------------------------------------------
// Gate: fp32 conv -> sigmoid -> top2 -> softmax -> dense score_full.
// (unchanged this round)
// ---------------------------------------------------------------------------
__global__ __launch_bounds__(256) void gate_kernel(
    const float* __restrict__ x, const float* __restrict__ gw,
    const float* __restrict__ gb, float* __restrict__ scores)
{
    __shared__ float gws[9216];          // [ci][tap][e] — wave-uniform reads
    __shared__ float red[4][64][8];      // partial sums per ci-group

    const int t = threadIdx.x;
    for (int i = t; i < 9216; i += 256) {
        int ci  = i / 72;
        int r   = i - ci * 72;
        int tap = r >> 3;
        int e   = r & 7;
        gws[i] = gw[(e * 128 + ci) * 9 + tap];
    }
    __syncthreads();

    const int g  = t >> 6;               // ci group (wave id)
    const int p  = t & 63;
    const int bx = blockIdx.x;
    const int wt = bx % 3;
    const int h2 = (bx / 3) % 48;
    const int b  = bx / 144;
    const int h  = h2 * 2 + (p >> 5);
    const int w  = wt * 32 + (p & 31);

    int off[9]; float msk[9];
    #pragma unroll
    for (int kh = 0; kh < 3; kh++) {
        #pragma unroll
        for (int kw = 0; kw < 3; kw++) {
            int hh = h + kh - 1, ww = w + kw - 1;
            bool valid = (hh >= 0 && hh < 96 && ww >= 0 && ww < 96);
            int hc = min(max(hh, 0), 95), wc = min(max(ww, 0), 95);
            off[kh * 3 + kw] = hc * 96 + wc;
            msk[kh * 3 + kw] = valid ? 1.0f : 0.0f;
        }
    }

    const float* xb = x + (b * 128 + g * 32) * 9216;
    float acc[8] = {0.f,0.f,0.f,0.f,0.f,0.f,0.f,0.f};
    #pragma unroll 2
    for (int ci = 0; ci < 32; ci++) {
        const float* xc = xb + ci * 9216;
        const float* wr = &gws[(g * 32 + ci) * 72];
        float xv[9];
        #pragma unroll
        for (int tap = 0; tap < 9; tap++) xv[tap] = xc[off[tap]] * msk[tap];
        #pragma unroll
        for (int tap = 0; tap < 9; tap++) {
            #pragma unroll
            for (int e = 0; e < 8; e++) acc[e] += xv[tap] * wr[tap * 8 + e];
        }
    }

    #pragma unroll
    for (int e = 0; e < 8; e++) red[g][p][e] = acc[e];
    __syncthreads();

    if (t < 64) {
        float s[8], bs[8];
        #pragma unroll
        for (int e = 0; e < 8; e++) {
            float v = red[0][t][e] + red[1][t][e] + red[2][t][e] + red[3][t][e];
            s[e]  = 1.0f / (1.0f + expf(-v));
            bs[e] = s[e] + gb[e];
        }
        int i1 = 0; float b1 = bs[0]; float w1 = s[0];
        #pragma unroll
        for (int e = 1; e < 8; e++)
            if (bs[e] > b1) { b1 = bs[e]; i1 = e; w1 = s[e]; }
        int i2 = -1; float b2 = -1e30f; float w2 = 0.f;
        #pragma unroll
        for (int e = 0; e < 8; e++)
            if (e != i1 && bs[e] > b2) { b2 = bs[e]; i2 = e; w2 = s[e]; }

        float mx = fmaxf(w1, w2);
        float e1 = expf(w1 - mx), e2 = expf(w2 - mx);
        float inv = 1.0f / (e1 + e2);
        float p1 = e1 * inv, p2 = e2 * inv;   // ROUTE_SCALE = 1

        const int hh = h2 * 2 + (t >> 5);
        const int ww = wt * 32 + (t & 31);
        int base = b * 8 * 9216 + hh * 96 + ww;
        #pragma unroll
        for (int e = 0; e < 8; e++) {
            float v = (e == i1) ? p1 : ((e == i2) ? p2 : 0.0f);
            scores[base + e * 9216] = v;
        }
    }
}

// ---------------------------------------------------------------------------
// Main v2: fused dense MoE conv via implicit-GEMM MFMA.
// Weights are NOT staged in LDS: each wave loads its 8 A-fragments per
// (expert,tap) straight from the fragment-ordered pw buffer (L2-resident,
// perfectly coalesced dwordx4), double-buffered in registers across taps.
// The main loop is barrier-free; only x stays in LDS (read-only after one
// initial __syncthreads). LDS/block 43.6 KB -> 3 blocks/CU.
// ---------------------------------------------------------------------------
__global__ __launch_bounds__(256, 3) void moe_main_kernel(
    const float* __restrict__ x, const unsigned short* __restrict__ pw,
    const float* __restrict__ scores, const float* __restrict__ eb,
    const float* __restrict__ sb, float* __restrict__ out)
{
    __shared__ unsigned short xs[4 * 34 * 136]; // [row(4)][col(34)][ci 128 pad->136]
    __shared__ float sc[8][64];
    __shared__ float bia[9][128];

    const int t  = threadIdx.x;
    const int bx = blockIdx.x;
    const int wt = bx % 3;
    const int h2 = (bx / 3) % 48;
    const int b  = bx / 144;
    const int h0 = h2 * 2, w0 = wt * 32;

    // ---- stage x patch (4 rows x 34 cols x 128 ci), fp32 -> bf16, transposed
    const float* xb = x + b * 128 * 9216;
    for (int i = t; i < 17408; i += 256) {
        int ci  = i / 136;
        int rem = i - ci * 136;
        int row = rem / 34;
        int col = rem - row * 34;
        int hh = h0 - 1 + row;
        int ww = w0 - 1 + col;
        float v = 0.0f;
        if (hh >= 0 && hh < 96 && ww >= 0 && ww < 96)
            v = xb[ci * 9216 + hh * 96 + ww];
        xs[(row * 34 + col) * 136 + ci] = f2bf(v);
    }
    // ---- stage routing scores for the 64 pixels
    for (int i = t; i < 512; i += 256) {
        int e = i >> 6, p = i & 63;
        sc[e][p] = scores[(b * 8 + e) * 9216 + (h0 + (p >> 5)) * 96 + (w0 + (p & 31))];
    }
    // ---- stage biases (experts + shared as e=8)
    for (int i = t; i < 1152; i += 256) {
        int e = i >> 7, co = i & 127;
        bia[e][co] = (e < 8) ? eb[(e << 7) + co] : sb[co];
    }
    __syncthreads();

    const int wv = t >> 6;
    const int l  = t & 63;
    const int lm = l & 15;   // m (A: co) / n (B: pixel) within frag
    const int lq = l >> 4;   // k-subgroup for A/B; row-group for D

    f32x4 acc[2][4], accE[2][4];
    #pragma unroll
    for (int i2 = 0; i2 < 2; i2++)
        #pragma unroll
        for (int j = 0; j < 4; j++) {
            acc[i2][j]  = (f32x4){0.f, 0.f, 0.f, 0.f};
            accE[i2][j] = (f32x4){0.f, 0.f, 0.f, 0.f};
        }

    const int bBase = lm * 136 + lq * 8;
    // per-wave, per-lane base into the fragment-ordered weight buffer
    const uint4* pw4 = reinterpret_cast<const uint4*>(pw) + wv * 512 + l;

    uint4 afA[8], afB[8];   // [kc*2+h] — all indexing compile-time (regs)

#define LOADF(dst, etv) {                                                     \
    const uint4* _p = pw4 + (etv) * 2048;                                     \
    _Pragma("unroll")                                                         \
    for (int q = 0; q < 8; ++q) dst[q] = _p[(q >> 1) * 128 + (q & 1) * 64];   \
}

#define COMPUTE(src, etv) {                                                   \
    const int e_   = (etv) / 9;                                               \
    const int tap_ = (etv) - e_ * 9;                                          \
    const int kh_  = tap_ / 3;                                                \
    const int kw_  = tap_ - kh_ * 3;                                          \
    const int xr0  = kh_ * 4624 + kw_ * 136 + bBase;                          \
    _Pragma("unroll")                                                         \
    for (int kc = 0; kc < 4; ++kc) {                                          \
        short8 a0 = *reinterpret_cast<const short8*>(&src[kc * 2 + 0]);       \
        short8 a1 = *reinterpret_cast<const short8*>(&src[kc * 2 + 1]);       \
        _Pragma("unroll")                                                     \
        for (int j = 0; j < 4; ++j) {                                         \
            short8 bv = *reinterpret_cast<const short8*>(                     \
                &xs[xr0 + (j >> 1) * 4624 + (j & 1) * 2176 + kc * 32]);       \
            accE[0][j] = __builtin_amdgcn_mfma_f32_16x16x32_bf16(             \
                a0, bv, accE[0][j], 0, 0, 0);                                 \
            accE[1][j] = __builtin_amdgcn_mfma_f32_16x16x32_bf16(             \
                a1, bv, accE[1][j], 0, 0, 0);                                 \
        }                                                                     \
    }                                                                         \
    if (tap_ == 8) {  /* end of expert: weighted accumulate */                \
        _Pragma("unroll")                                                     \
        for (int j = 0; j < 4; ++j) {                                         \
            const float s_ = (e_ < 8) ? sc[e_][j * 16 + lm] : 1.0f;           \
            _Pragma("unroll")                                                 \
            for (int i2 = 0; i2 < 2; ++i2)                                    \
                _Pragma("unroll")                                             \
                for (int rr = 0; rr < 4; ++rr) {                              \
                    const int co_ = wv * 32 + i2 * 16 + lq * 4 + rr;          \
                    acc[i2][j][rr] += s_ * (accE[i2][j][rr] + bia[e_][co_]);  \
                    accE[i2][j][rr] = 0.f;                                    \
                }                                                             \
        }                                                                     \
    }                                                                         \
}

    // barrier-free main loop: 81 (expert,tap) steps, A-frags double-buffered
    LOADF(afA, 0);
    for (int eu = 0; eu < 40; ++eu) {
        const int et0 = eu * 2;
        LOADF(afB, et0 + 1);
        COMPUTE(afA, et0);
        LOADF(afA, et0 + 2);     // et0+2 <= 80
        COMPUTE(afB, et0 + 1);
    }
    COMPUTE(afA, 80);
#undef LOADF
#undef COMPUTE

    // ---- store (D frag: col = lm -> pixel, row = lq*4+rr -> co)
    float* ob = out + b * 128 * 9216;
    #pragma unroll
    for (int i2 = 0; i2 < 2; i2++)
        #pragma unroll
        for (int rr = 0; rr < 4; rr++) {
            const int co = wv * 32 + i2 * 16 + lq * 4 + rr;
            #pragma unroll
            for (int j = 0; j < 4; j++) {
                const int hh = h0 + (j >> 1);
                const int ww = w0 + (j & 1) * 16 + lm;
                ob[co * 9216 + hh * 96 + ww] = acc[i2][j][rr];
            }
        }
}

// ---------------------------------------------------------------------------
extern "C" void kernel_launch(void* const* d_in, const int* in_sizes, int n_in,
                              void* d_out, int out_size, void* d_ws, size_t ws_size,
                              hipStream_t stream) {
    const float* x  = (const float*)d_in[0];
    const float* gw = (const float*)d_in[1];
    const float* gb = (const float*)d_in[2];
    const float* ew = (const float*)d_in[3];
    const float* eb = (const float*)d_in[4];
    const float* sw = (const float*)d_in[5];
    const float* sb = (const float*)d_in[6];
    float* out = (float*)d_out;

    unsigned short* pw = (unsigned short*)d_ws;                  // 2,654,208 B
    float* scores = (float*)((char*)d_ws + 2654208);             // 1,179,648 B

    prep_kernel<<<648, 256, 0, stream>>>(ew, sw, pw);
    gate_kernel<<<576, 256, 0, stream>>>(x, gw, gb, scores);
    moe_main_kernel<<<576, 256, 0, stream>>>(x, pw, scores, eb, sb, out);
}